// Round 5
// baseline (39.420 us; speedup 1.0000x reference)
//
#include <hip/hip_runtime.h>
#include <math.h>

#define E_CNT 1999
#define N_PTS 2000
#define B_CNT 8
#define M_CNT (2*E_CNT)                    // 3998 combined signed edges
#define MPAD 4096                          // padded (zero-filled) edge count
#define NTILES 16                          // 256-row tiles over MPAD
#define NTP 136                            // upper-triangle tile pairs
#define NCHUNK 8                           // 32-col chunks per 256-col tile
#define PAIR_BLOCKS (B_CNT*NTP*NCHUNK)     // 8704
#define PRE_BLOCKS  (B_CNT*16)             // 128
#define NPART (PAIR_BLOCKS + PRE_BLOCKS)   // 8832

#define CEXP  (-5.7707801635558535f)       // -4 * log2(e)
#define NEG2C (11.541560327111707f)        // -2 * CEXP

// Per edge p of sample b, two float4 in scratch:
//   ecu[2*(b*MPAD+p)+0] = (cx, cy, cz, B)  B = CEXP*|c|^2
//   ecu[2*(b*MPAD+p)+1] = (ux*sqrt(l), uy*sqrt(l), uz*sqrt(l), s)  s=+-1 (0 pad)
// Each block writes its partial (diag l^2 sum + SRNF) to its own slot.
__global__ __launch_bounds__(256) void pre_kernel(
    const float* __restrict__ outp, const float* __restrict__ tgtp,
    const float* __restrict__ tmpl, float4* __restrict__ ecu,
    float* __restrict__ part)
{
    int b = blockIdx.x >> 4;
    int p = ((blockIdx.x & 15) << 8) + threadIdx.x;   // 0..4095

    float val = 0.f;
    float4 C = make_float4(0.f, 0.f, 0.f, 0.f);
    float4 U = make_float4(0.f, 0.f, 0.f, 0.f);

    if (p < M_CNT) {
        float ax, ay, az, bx, by, bz;
        bool isX = (p < E_CNT);
        if (isX) {
            const float* o0 = outp + ((size_t)b * N_PTS + p) * 3;
            const float* t0 = tmpl + (size_t)p * 3;
            ax = o0[0] + t0[0]; ay = o0[1] + t0[1]; az = o0[2] + t0[2];
            bx = o0[3] + t0[3]; by = o0[4] + t0[4]; bz = o0[5] + t0[5];
        } else {
            int e = p - E_CNT;
            const float* g0 = tgtp + ((size_t)b * N_PTS + e) * 3;
            ax = g0[0]; ay = g0[1]; az = g0[2];
            bx = g0[3]; by = g0[4]; bz = g0[5];
        }
        float cx = 0.5f * (ax + bx), cy = 0.5f * (ay + by), cz = 0.5f * (az + bz);
        float tx = bx - ax, ty = by - ay, tz = bz - az;
        float l2 = tx * tx + ty * ty + tz * tz + 1e-12f;
        float l  = sqrtf(l2);
        float rs = rsqrtf(l);                 // 1/sqrt(l);  u*sqrt(l) = t/sqrt(l)
        C = make_float4(cx, cy, cz, CEXP * (cx * cx + cy * cy + cz * cz));
        U = make_float4(tx * rs, ty * rs, tz * rs, isX ? 1.f : -1.f);
        val = l * l;
        if (isX) {
            const float* t0 = tmpl + (size_t)p * 3;
            float txT = t0[3] - t0[0], tyT = t0[4] - t0[1], tzT = t0[5] - t0[2];
            float lT = sqrtf(txT * txT + tyT * tyT + tzT * tzT + 1e-12f);
            float rT = rsqrtf(lT);
            float dqx = tx * rs - txT * rT;
            float dqy = ty * rs - tyT * rT;
            float dqz = tz * rs - tzT * rT;
            val += 1e-7f * (dqx * dqx + dqy * dqy + dqz * dqz);
        }
    }
    size_t base = 2 * ((size_t)b * MPAD + p);
    ecu[base]     = C;
    ecu[base + 1] = U;

    for (int off = 32; off; off >>= 1) val += __shfl_down(val, off);
    __shared__ float red[4];
    int lane = threadIdx.x & 63, wid = threadIdx.x >> 6;
    if (lane == 0) red[wid] = val;
    __syncthreads();
    if (threadIdx.x == 0)
        part[PAIR_BLOCKS + blockIdx.x] = (red[0] + red[1]) + (red[2] + red[3]);
}

// Strict-upper-triangle pair sum (x2). One wave per block: 256 rows (R=4/lane)
// x 32 cols. Cols staged wave-privately in LDS; s*exp2(B) folded at staging.
// Inner: 9 VALU + 1 exp2 per pair; 2 ds_read_b128 serve 256 pairs.
__global__ __launch_bounds__(64) void pair_kernel(
    const float4* __restrict__ ecu, float* __restrict__ part)
{
    __shared__ float4 sCU[64];   // even: (cx,cy,cz,kw=s*exp2(B)); odd: (u'x,u'y,u'z,-)

    int id = blockIdx.x;
    int b  = id / (NTP * NCHUNK);
    int r  = id % (NTP * NCHUNK);
    int tp = r >> 3, ch = r & 7;
    int rt = 0, rem = tp;
    while (rem >= NTILES - rt) { rem -= NTILES - rt; ++rt; }
    int ct = rt + rem;

    int lane = threadIdx.x;
    const float4* __restrict__ eb = ecu + (size_t)b * MPAD * 2;

    // stage 32 columns = 64 consecutive float4s (one per lane), fold kw
    int j0 = ct * 256 + ch * 32;
    {
        float4 v = eb[2 * j0 + lane];
        float sw = __shfl(v.w, lane | 1);          // sign from the U slot
        if (!(lane & 1)) v.w = sw * __builtin_amdgcn_exp2f(v.w);
        sCU[lane] = v;
    }

    // 4 rows per lane
    float chx[4], chy[4], chz[4], rB[4], rux[4], ruy[4], ruz[4], rs4[4];
    int ri[4];
    #pragma unroll
    for (int k = 0; k < 4; ++k) {
        int i = rt * 256 + k * 64 + lane;
        ri[k] = i;
        float4 C = eb[2 * i];
        float4 U = eb[2 * i + 1];
        chx[k] = NEG2C * C.x; chy[k] = NEG2C * C.y; chz[k] = NEG2C * C.z;
        rB[k] = C.w;
        rux[k] = U.x; ruy[k] = U.y; ruz[k] = U.z; rs4[k] = U.w;
    }
    __syncthreads();

    float av[4] = {0.f, 0.f, 0.f, 0.f};

    if (rt != ct) {
        #pragma unroll 4
        for (int jj = 0; jj < 32; ++jj) {
            float4 cc = sCU[2 * jj];
            float4 cu = sCU[2 * jj + 1];
            #pragma unroll
            for (int k = 0; k < 4; ++k) {
                float arg = fmaf(chx[k], cc.x, rB[k]);
                arg = fmaf(chy[k], cc.y, arg);
                arg = fmaf(chz[k], cc.z, arg);
                float E  = __builtin_amdgcn_exp2f(arg);
                float du = rux[k] * cu.x;
                du = fmaf(ruy[k], cu.y, du);
                du = fmaf(ruz[k], cu.z, du);
                float m = du * du * cc.w;
                av[k] = fmaf(E, m, av[k]);
            }
        }
    } else {
        #pragma unroll 4
        for (int jj = 0; jj < 32; ++jj) {
            float4 cc = sCU[2 * jj];
            float4 cu = sCU[2 * jj + 1];
            int j = j0 + jj;
            #pragma unroll
            for (int k = 0; k < 4; ++k) {
                float kw = (j > ri[k]) ? cc.w : 0.f;   // strict upper triangle
                float arg = fmaf(chx[k], cc.x, rB[k]);
                arg = fmaf(chy[k], cc.y, arg);
                arg = fmaf(chz[k], cc.z, arg);
                float E  = __builtin_amdgcn_exp2f(arg);
                float du = rux[k] * cu.x;
                du = fmaf(ruy[k], cu.y, du);
                du = fmaf(ruz[k], cu.z, du);
                float m = du * du * kw;
                av[k] = fmaf(E, m, av[k]);
            }
        }
    }

    float thr = av[0] * rs4[0] + av[1] * rs4[1] + av[2] * rs4[2] + av[3] * rs4[3];
    thr *= 2.0f;
    for (int off = 32; off; off >>= 1) thr += __shfl_down(thr, off);
    if (lane == 0) part[id] = thr;
}

__global__ __launch_bounds__(256) void final_kernel(
    const float* __restrict__ part, float* __restrict__ outv)
{
    float s = 0.f;
    for (int i = threadIdx.x; i < NPART; i += 256) s += part[i];
    for (int off = 32; off; off >>= 1) s += __shfl_down(s, off);
    __shared__ float red[4];
    int lane = threadIdx.x & 63, wid = threadIdx.x >> 6;
    if (lane == 0) red[wid] = s;
    __syncthreads();
    if (threadIdx.x == 0)
        outv[0] = 0.125f * ((red[0] + red[1]) + (red[2] + red[3]));
}

extern "C" void kernel_launch(void* const* d_in, const int* in_sizes, int n_in,
                              void* d_out, int out_size, void* d_ws, size_t ws_size,
                              hipStream_t stream)
{
    const float* outp = (const float*)d_in[0];  // (8,2000,3) f32
    const float* tgtp = (const float*)d_in[1];  // (8,2000,3) f32
    const float* tmpl = (const float*)d_in[3];  // (2000,3) f32
    float* part = (float*)d_ws;                              // 8832 floats
    float4* ecu = (float4*)((char*)d_ws + 65536);            // 1 MiB edge data

    pre_kernel<<<PRE_BLOCKS, 256, 0, stream>>>(outp, tgtp, tmpl, ecu, part);
    pair_kernel<<<PAIR_BLOCKS, 64, 0, stream>>>(ecu, part);
    final_kernel<<<1, 256, 0, stream>>>(part, (float*)d_out);
}

// Round 6
// 34.321 us; speedup vs baseline: 1.1486x; 1.1486x over previous
//
#include <hip/hip_runtime.h>
#include <math.h>

#define E_CNT 1999
#define N_PTS 2000
#define B_CNT 8
#define SEG 2048                           // X edges in [0,SEG), target edges in [SEG,2*SEG)
#define MPAD (2*SEG)                       // 4096 padded combined edges
#define NTILES 16                          // 256-row tiles
#define NTP 136                            // upper-triangle tile pairs
#define PAIR_BLOCKS (B_CNT*NTP)            // 1088
#define PRE_BLOCKS  (B_CNT*16)             // 128
#define NPART (PAIR_BLOCKS + PRE_BLOCKS)   // 1216

#define HCEXP (-2.8853900817779268f)       // -2*log2(e) = CEXP/2
#define NEG2C (11.541560327111707f)        // +8*log2(e)

// Per edge slot s of sample b:
//   eA[b*MPAD+s] = (cx, cy, cz, u''x)
//   eB[b*MPAD+s] = (u''y, u''z)
// where u'' = (t/sqrt(l)) * exp2(HCEXP*|c|^2).  Pads are all-zero.
// Each pre block also writes its partial (sum l^2 + SRNF) to part[].
__global__ __launch_bounds__(256) void pre_kernel(
    const float* __restrict__ outp, const float* __restrict__ tgtp,
    const float* __restrict__ tmpl, float4* __restrict__ eA,
    float2* __restrict__ eB, float* __restrict__ part)
{
    int b = blockIdx.x >> 4;
    int p = ((blockIdx.x & 15) << 8) + threadIdx.x;   // 0..4095

    float val = 0.f;
    float4 A = make_float4(0.f, 0.f, 0.f, 0.f);
    float2 Bv = make_float2(0.f, 0.f);

    bool isX = (p < SEG);
    int e = isX ? p : p - SEG;
    if (e < E_CNT) {
        float ax, ay, az, bx, by, bz;
        if (isX) {
            const float* o0 = outp + ((size_t)b * N_PTS + e) * 3;
            const float* t0 = tmpl + (size_t)e * 3;
            ax = o0[0] + t0[0]; ay = o0[1] + t0[1]; az = o0[2] + t0[2];
            bx = o0[3] + t0[3]; by = o0[4] + t0[4]; bz = o0[5] + t0[5];
        } else {
            const float* g0 = tgtp + ((size_t)b * N_PTS + e) * 3;
            ax = g0[0]; ay = g0[1]; az = g0[2];
            bx = g0[3]; by = g0[4]; bz = g0[5];
        }
        float cx = 0.5f * (ax + bx), cy = 0.5f * (ay + by), cz = 0.5f * (az + bz);
        float tx = bx - ax, ty = by - ay, tz = bz - az;
        float l2 = tx * tx + ty * ty + tz * tz + 1e-12f;
        float l  = sqrtf(l2);
        float rs = rsqrtf(l);                                 // 1/sqrt(l)
        float f  = __builtin_amdgcn_exp2f(HCEXP * (cx * cx + cy * cy + cz * cz));
        float g  = rs * f;
        A  = make_float4(cx, cy, cz, tx * g);
        Bv = make_float2(ty * g, tz * g);
        val = l * l;
        if (isX) {
            const float* t0 = tmpl + (size_t)e * 3;
            float txT = t0[3] - t0[0], tyT = t0[4] - t0[1], tzT = t0[5] - t0[2];
            float lT = sqrtf(txT * txT + tyT * tyT + tzT * tzT + 1e-12f);
            float rT = rsqrtf(lT);
            float dqx = tx * rs - txT * rT;                   // q = t/sqrt(l)
            float dqy = ty * rs - tyT * rT;
            float dqz = tz * rs - tzT * rT;
            val += 1e-7f * (dqx * dqx + dqy * dqy + dqz * dqz);
        }
    }
    size_t s = (size_t)b * MPAD + p;
    eA[s] = A;
    eB[s] = Bv;

    for (int off = 32; off; off >>= 1) val += __shfl_down(val, off);
    __shared__ float red[4];
    int lane = threadIdx.x & 63, wid = threadIdx.x >> 6;
    if (lane == 0) red[wid] = val;
    __syncthreads();
    if (threadIdx.x == 0)
        part[PAIR_BLOCKS + blockIdx.x] = (red[0] + red[1]) + (red[2] + red[3]);
}

#define PAIR_CORE(AV)                                                        \
    {                                                                        \
        float arg = chx[0] * a0.x;  arg = fmaf(chy[0], a0.y, arg);           \
        arg = fmaf(chz[0], a0.z, arg);                                       \
        float E = __builtin_amdgcn_exp2f(arg);                               \
        float du = rux[0] * a0.w;  du = fmaf(ruy[0], b0.x, du);              \
        du = fmaf(ruz[0], b0.y, du);  AV(0);                                 \
    }

// Strict-upper-triangle pair sum (x2 folded into sign).  256-thread blocks:
// 4 waves share a 256-col LDS tile (b128+b64 packed); each wave owns a
// 64-col quarter; each lane owns 4 rows.  Inner: 8 VALU + 1 exp2 per pair,
// with 1-ahead register prefetch of column data.
__global__ __launch_bounds__(256) void pair_kernel(
    const float4* __restrict__ eA, const float2* __restrict__ eB,
    float* __restrict__ part)
{
    __shared__ float4 sA[256];
    __shared__ float2 sB[256];
    __shared__ float  red[4];

    int id = blockIdx.x;
    int b = id / NTP;
    int t = id % NTP;
    int rt = 0, rem = t;
    while (rem >= NTILES - rt) { rem -= NTILES - rt; ++rt; }
    int ct = rt + rem;

    int tid = threadIdx.x, lane = tid & 63, w = tid >> 6;
    const float4* __restrict__ ebA = eA + (size_t)b * MPAD;
    const float2* __restrict__ ebB = eB + (size_t)b * MPAD;

    // stage the 256-column tile
    {
        int cj = ct * 256 + tid;
        sA[tid] = ebA[cj];
        sB[tid] = ebB[cj];
    }

    // 4 rows per lane in registers
    float chx[4], chy[4], chz[4], rux[4], ruy[4], ruz[4];
    int ri[4];
    #pragma unroll
    for (int k = 0; k < 4; ++k) {
        int i = rt * 256 + k * 64 + lane;
        ri[k] = i;
        float4 A = ebA[i];
        float2 Bv = ebB[i];
        chx[k] = NEG2C * A.x; chy[k] = NEG2C * A.y; chz[k] = NEG2C * A.z;
        rux[k] = A.w; ruy[k] = Bv.x; ruz[k] = Bv.y;
    }
    __syncthreads();

    float av[4] = {0.f, 0.f, 0.f, 0.f};
    int jl0 = w * 64;            // this wave's quarter
    int j0  = ct * 256 + jl0;    // global column base

    if (rt != ct) {
        float4 a0 = sA[jl0];
        float2 b0 = sB[jl0];
        #pragma unroll 4
        for (int jj = 0; jj < 63; ++jj) {
            float4 a1 = sA[jl0 + jj + 1];      // prefetch next column
            float2 b1 = sB[jl0 + jj + 1];
            #pragma unroll
            for (int k = 0; k < 4; ++k) {
                float arg = chx[k] * a0.x;
                arg = fmaf(chy[k], a0.y, arg);
                arg = fmaf(chz[k], a0.z, arg);
                float E = __builtin_amdgcn_exp2f(arg);
                float du = rux[k] * a0.w;
                du = fmaf(ruy[k], b0.x, du);
                du = fmaf(ruz[k], b0.y, du);
                av[k] = fmaf(E, du * du, av[k]);
            }
            a0 = a1; b0 = b1;
        }
        #pragma unroll
        for (int k = 0; k < 4; ++k) {          // epilogue column
            float arg = chx[k] * a0.x;
            arg = fmaf(chy[k], a0.y, arg);
            arg = fmaf(chz[k], a0.z, arg);
            float E = __builtin_amdgcn_exp2f(arg);
            float du = rux[k] * a0.w;
            du = fmaf(ruy[k], b0.x, du);
            du = fmaf(ruz[k], b0.y, du);
            av[k] = fmaf(E, du * du, av[k]);
        }
    } else {
        float4 a0 = sA[jl0];
        float2 b0 = sB[jl0];
        #pragma unroll 4
        for (int jj = 0; jj < 64; ++jj) {
            float4 a1 = sA[(jl0 + jj + 1) & 255];
            float2 b1 = sB[(jl0 + jj + 1) & 255];
            int j = j0 + jj;
            #pragma unroll
            for (int k = 0; k < 4; ++k) {
                float arg = chx[k] * a0.x;
                arg = fmaf(chy[k], a0.y, arg);
                arg = fmaf(chz[k], a0.z, arg);
                float E = __builtin_amdgcn_exp2f(arg);
                float du = rux[k] * a0.w;
                du = fmaf(ruy[k], b0.x, du);
                du = fmaf(ruz[k], b0.y, du);
                float m = (j > ri[k]) ? du * du : 0.f;   // strict upper
                av[k] = fmaf(E, m, av[k]);
            }
            a0 = a1; b0 = b1;
        }
    }

    // sign: +1 for both tiles in same segment, -1 for cross; x2 symmetric
    float sgn = ((rt < 8) == (ct < 8)) ? 2.f : -2.f;
    float thr = sgn * ((av[0] + av[1]) + (av[2] + av[3]));
    for (int off = 32; off; off >>= 1) thr += __shfl_down(thr, off);
    if (lane == 0) red[w] = thr;
    __syncthreads();
    if (tid == 0)
        part[id] = (red[0] + red[1]) + (red[2] + red[3]);
}

__global__ __launch_bounds__(256) void final_kernel(
    const float* __restrict__ part, float* __restrict__ outv)
{
    float s = 0.f;
    for (int i = threadIdx.x; i < NPART; i += 256) s += part[i];
    for (int off = 32; off; off >>= 1) s += __shfl_down(s, off);
    __shared__ float red[4];
    int lane = threadIdx.x & 63, wid = threadIdx.x >> 6;
    if (lane == 0) red[wid] = s;
    __syncthreads();
    if (threadIdx.x == 0)
        outv[0] = 0.125f * ((red[0] + red[1]) + (red[2] + red[3]));
}

extern "C" void kernel_launch(void* const* d_in, const int* in_sizes, int n_in,
                              void* d_out, int out_size, void* d_ws, size_t ws_size,
                              hipStream_t stream)
{
    const float* outp = (const float*)d_in[0];  // (8,2000,3) f32
    const float* tgtp = (const float*)d_in[1];  // (8,2000,3) f32
    const float* tmpl = (const float*)d_in[3];  // (2000,3) f32
    float*  part = (float*)d_ws;                             // 1216 floats
    float4* eA   = (float4*)((char*)d_ws + 65536);           // 512 KiB
    float2* eB   = (float2*)((char*)d_ws + 65536 + 524288);  // 256 KiB

    pre_kernel<<<PRE_BLOCKS, 256, 0, stream>>>(outp, tgtp, tmpl, eA, eB, part);
    pair_kernel<<<PAIR_BLOCKS, 256, 0, stream>>>(eA, eB, part);
    final_kernel<<<1, 256, 0, stream>>>(part, (float*)d_out);
}